// Round 2
// baseline (1563.400 us; speedup 1.0000x reference)
//
#include <hip/hip_runtime.h>
#include <hip/hip_bf16.h>
#include <stdint.h>

#define B_ 8192
#define T_ 21
#define F_ 3
#define U_ 512

typedef _Float16 f16x8 __attribute__((ext_vector_type(8)));
typedef float f32x4 __attribute__((ext_vector_type(4)));

__device__ __forceinline__ float fsigmoid(float x) { return 1.0f / (1.0f + __expf(-x)); }
__device__ __forceinline__ float ftanh_(float x) {
  float t = __expf(-2.0f * fabsf(x));
  float r = (1.0f - t) / (1.0f + t);
  return x < 0.0f ? -r : r;
}

__device__ __forceinline__ void gl_lds16(const void* g, void* l) {
  __builtin_amdgcn_global_load_lds((__attribute__((address_space(1))) void*)g,
                                   (__attribute__((address_space(3))) void*)l, 16, 0, 0);
}

// ---------------------------------------------------------------------------
// prep: transpose+pack weights to f16, pack kernel/bias with gate interleave
// packed col p for (gate g, unit u): p = 64*(u/16) + 16*g + (u%16)
// orig(p) = ((p>>4)&3)*512 + ((p>>6)<<4) + (p&15)
// ---------------------------------------------------------------------------
__global__ void prep_weights(const float* __restrict__ Wr, const float* __restrict__ wrnn,
                             const float* __restrict__ urnn, const float* __restrict__ kern,
                             const float* __restrict__ bias,
                             _Float16* __restrict__ WrT, _Float16* __restrict__ W2T,
                             float* __restrict__ Kp, float* __restrict__ bp) {
  size_t i = (size_t)blockIdx.x * 256 + threadIdx.x;
  if (i < (size_t)2048 * 512) {
    int p = (int)(i >> 9), k = (int)(i & 511);
    int orig = ((p >> 4) & 3) * 512 + ((p >> 6) << 4) + (p & 15);
    WrT[i] = (_Float16)Wr[(size_t)k * 2048 + orig];
  }
  if (i < (size_t)512 * 1024) {
    int n = (int)(i >> 10), k = (int)(i & 1023);
    float v = (k < 512) ? wrnn[(size_t)k * 512 + n] : urnn[(size_t)(k - 512) * 512 + n];
    W2T[i] = (_Float16)v;
  }
  if (i < 2048) {
    int p = (int)i;
    int orig = ((p >> 4) & 3) * 512 + ((p >> 6) << 4) + (p & 15);
    Kp[p] = kern[orig];
    Kp[2048 + p] = kern[2048 + orig];
    Kp[4096 + p] = kern[4096 + orig];
    bp[p] = bias[orig];
  }
}

__global__ void prep_wv(const float* __restrict__ wfc, const float* __restrict__ bfc,
                        const float* __restrict__ wout, const float* __restrict__ bout,
                        float* __restrict__ wv) {
  int u = blockIdx.x * 256 + threadIdx.x;
  if (u < 512) {
    float s = 0.0f;
    for (int k = 0; k < 32; ++k) s += wfc[u * 32 + k] * wout[k];
    wv[u] = s;
  }
  if (u == 0) {
    float s = 0.0f;
    for (int k = 0; k < 32; ++k) s += bfc[k] * wout[k];
    wv[512] = s + bout[0];
  }
}

// ---------------------------------------------------------------------------
// mask + o_idx (cummax of learned-row index, forward fill, first-fill)
// one block (1024 thr) per timestep; each thread owns 8 consecutive rows
// ---------------------------------------------------------------------------
__global__ void prep_mask(const int* __restrict__ lt, int* __restrict__ orow,
                          signed char* __restrict__ mm) {
  const int t = blockIdx.x;
  const int tid = threadIdx.x;
  __shared__ int sh[1024];
  __shared__ int s_any, s_first;
  if (tid == 0) { s_any = 0; s_first = 0x7fffffff; }
  __syncthreads();
  const int base = tid * 8;
  const int* row = lt + (size_t)t * B_ + base;
  int bits = 0;
#pragma unroll
  for (int j = 0; j < 8; ++j) bits |= (row[j] == 1) << j;
  if (bits) atomicOr(&s_any, 1);
  __syncthreads();
  if (tid == 0 && !s_any) bits |= 1;  // force row 0 learned
  int lf = bits ? (base + __ffs(bits) - 1) : 0x7fffffff;
  if (lf != 0x7fffffff) atomicMin(&s_first, lf);
  int lmax = -1;
#pragma unroll
  for (int j = 0; j < 8; ++j)
    if ((bits >> j) & 1) lmax = base + j;
  sh[tid] = lmax;
  __syncthreads();
  for (int off = 1; off < 1024; off <<= 1) {
    int v = (tid >= off) ? sh[tid - off] : -1;
    __syncthreads();
    if (v > sh[tid]) sh[tid] = v;
    __syncthreads();
  }
  int prefix = (tid > 0) ? sh[tid - 1] : -1;
  int first = s_first;
  int run = prefix;
  int* orp = orow + (size_t)t * B_ + base;
  signed char* mp = mm + (size_t)t * B_ + base;
#pragma unroll
  for (int j = 0; j < 8; ++j) {
    if ((bits >> j) & 1) run = base + j;
    orp[j] = (run < 0) ? first : run;
    mp[j] = (signed char)((bits >> j) & 1);
  }
}

// ---------------------------------------------------------------------------
// GEMM 128x128 tile, BK=32, 4 waves (2x2), 16x16x32 f16 MFMA.
// MODE 0: LSTM  z = h @ WrT^T (+x@K+bias in epilogue), gate-interleaved cols,
//         lane-local c update, store sigmoid(zo) to og.
// MODE 1: RNN   z = [h|r] @ W2T^T, epilogue tanh(+b_rnn) -> rout.
// ---------------------------------------------------------------------------
template <int MODE>
__global__ __launch_bounds__(256, 2) void gemm_step(
    const _Float16* __restrict__ A0, const _Float16* __restrict__ A1,
    const _Float16* __restrict__ Wt, const float* __restrict__ x,
    const float* __restrict__ Kp, const float* __restrict__ bp,
    const signed char* __restrict__ mmask, float* __restrict__ cbuf,
    _Float16* __restrict__ og, const float* __restrict__ brnn,
    _Float16* __restrict__ rout, int t) {
  constexpr int K = (MODE == 0) ? 512 : 1024;
  constexpr int NT = K / 32;
  __shared__ __align__(16) _Float16 Alds[128 * 32];
  __shared__ __align__(16) _Float16 Blds[128 * 32];
  const int tid = threadIdx.x;
  const int w = tid >> 6, l = tid & 63;
  const int wm = w >> 1, wn = w & 1;
  const int mBase = blockIdx.x * 128;
  const int nBase = blockIdx.y * 128;
  f32x4 acc[4][4] = {};

  const int lr = l >> 2;        // 0..15  (row within 16-row chunk)
  const int lk = (l & 3) * 8;   // 0,8,16,24 (k element offset)
  const int ch0 = w * 2, ch1 = w * 2 + 1;  // this wave's two 1KB chunks

  for (int kt = 0; kt < NT; ++kt) {
    const int k0 = kt * 32;
    const _Float16* As;
    int koff;
    if (MODE == 1 && k0 >= 512) { As = A1; koff = k0 - 512; }
    else { As = A0; koff = k0; }
    __syncthreads();
    gl_lds16(As + (size_t)(mBase + ch0 * 16 + lr) * 512 + koff + lk, (char*)Alds + ch0 * 1024);
    gl_lds16(As + (size_t)(mBase + ch1 * 16 + lr) * 512 + koff + lk, (char*)Alds + ch1 * 1024);
    gl_lds16(Wt + (size_t)(nBase + ch0 * 16 + lr) * K + k0 + lk, (char*)Blds + ch0 * 1024);
    gl_lds16(Wt + (size_t)(nBase + ch1 * 16 + lr) * K + k0 + lk, (char*)Blds + ch1 * 1024);
    __syncthreads();
    f16x8 af[4], bf[4];
    const int frow = l & 15;
    const int fkb = (l >> 4) * 8;
#pragma unroll
    for (int m = 0; m < 4; ++m)
      af[m] = *(const f16x8*)&Alds[(wm * 64 + m * 16 + frow) * 32 + fkb];
#pragma unroll
    for (int n = 0; n < 4; ++n)
      bf[n] = *(const f16x8*)&Blds[(wn * 64 + n * 16 + frow) * 32 + fkb];
#pragma unroll
    for (int m = 0; m < 4; ++m)
#pragma unroll
      for (int n = 0; n < 4; ++n)
        acc[m][n] = __builtin_amdgcn_mfma_f32_16x16x32_f16(af[m], bf[n], acc[m][n], 0, 0, 0);
  }

  const int c_ = l & 15, rg = l >> 4;
  const int pB = nBase + wn * 64;
  if constexpr (MODE == 0) {
    const int u = (pB >> 6) * 16 + c_;
    float kf[4][3], bb[4];
#pragma unroll
    for (int n = 0; n < 4; ++n) {
      int p = pB + n * 16 + c_;
      kf[n][0] = Kp[p]; kf[n][1] = Kp[2048 + p]; kf[n][2] = Kp[4096 + p];
      bb[n] = bp[p];
    }
#pragma unroll
    for (int m = 0; m < 4; ++m) {
#pragma unroll
      for (int r = 0; r < 4; ++r) {
        int b = mBase + wm * 64 + m * 16 + rg * 4 + r;
        const float* xp = x + (size_t)b * (T_ * F_) + t * F_;
        float x0 = xp[0], x1 = xp[1], x2 = xp[2];
        float zi = acc[m][0][r] + x0 * kf[0][0] + x1 * kf[0][1] + x2 * kf[0][2] + bb[0];
        float zf = acc[m][1][r] + x0 * kf[1][0] + x1 * kf[1][1] + x2 * kf[1][2] + bb[1];
        float zg = acc[m][2][r] + x0 * kf[2][0] + x1 * kf[2][1] + x2 * kf[2][2] + bb[2];
        float zo = acc[m][3][r] + x0 * kf[3][0] + x1 * kf[3][1] + x2 * kf[3][2] + bb[3];
        float ig = fsigmoid(zi), fg = fsigmoid(zf);
        float gg = ftanh_(zg), ogv = fsigmoid(zo);
        size_t ci = (size_t)b * 512 + u;
        float cold = cbuf[ci];
        float cnew = mmask[b] ? (fg * cold + ig * gg) : cold;
        cbuf[ci] = cnew;
        og[ci] = (_Float16)ogv;
      }
    }
  } else {
#pragma unroll
    for (int m = 0; m < 4; ++m)
#pragma unroll
      for (int n = 0; n < 4; ++n) {
        int uu = pB + n * 16 + c_;
        float bn = brnn[uu];
#pragma unroll
        for (int r = 0; r < 4; ++r) {
          int b = mBase + wm * 64 + m * 16 + rg * 4 + r;
          rout[(size_t)b * 512 + uu] = (_Float16)ftanh_(acc[m][n][r] + bn);
        }
      }
  }
}

// h[b][u] = sigmoid_o[o_row[b]][u] * tanh(c[b][u])
__global__ void gather_h(const _Float16* __restrict__ og, const float* __restrict__ cbuf,
                         const int* __restrict__ orow, _Float16* __restrict__ h) {
  int g = blockIdx.x * 256 + threadIdx.x;
  int b = g >> 6, u0 = (g & 63) << 3;
  int src = orow[b];
  f16x8 ov = *(const f16x8*)(og + (size_t)src * 512 + u0);
  const float4* cp = (const float4*)(cbuf + (size_t)b * 512 + u0);
  float4 c0 = cp[0], c1 = cp[1];
  float cc[8] = {c0.x, c0.y, c0.z, c0.w, c1.x, c1.y, c1.z, c1.w};
  f16x8 hv;
#pragma unroll
  for (int j = 0; j < 8; ++j) hv[j] = (_Float16)((float)ov[j] * ftanh_(cc[j]));
  *(f16x8*)(h + (size_t)b * 512 + u0) = hv;
}

// out[b] = dot(r[b], wv) + c0  (one wave per row), fp32 output
__global__ void final_fc(const _Float16* __restrict__ r, const float* __restrict__ wv,
                         float* __restrict__ out) {
  int gw = (blockIdx.x * 256 + threadIdx.x) >> 6;
  int l = threadIdx.x & 63;
  const _Float16* rr = r + (size_t)gw * 512;
  f16x8 rv = *(const f16x8*)(rr + l * 8);
  const float4* wp = (const float4*)(wv + l * 8);
  float4 w0 = wp[0], w1 = wp[1];
  float wf[8] = {w0.x, w0.y, w0.z, w0.w, w1.x, w1.y, w1.z, w1.w};
  float s = 0.0f;
#pragma unroll
  for (int j = 0; j < 8; ++j) s += (float)rv[j] * wf[j];
  for (int o = 32; o; o >>= 1) s += __shfl_down(s, o);
  if (l == 0) out[gw] = s + wv[512];
}

extern "C" void kernel_launch(void* const* d_in, const int* in_sizes, int n_in,
                              void* d_out, int out_size, void* d_ws, size_t ws_size,
                              hipStream_t stream) {
  const float* x    = (const float*)d_in[0];
  const int*   lt   = (const int*)d_in[1];
  const float* kern = (const float*)d_in[2];
  const float* Wr   = (const float*)d_in[3];
  const float* bias = (const float*)d_in[4];
  const float* wrnn = (const float*)d_in[5];
  const float* urnn = (const float*)d_in[6];
  const float* brnn = (const float*)d_in[7];
  const float* wfc  = (const float*)d_in[8];
  const float* bfc  = (const float*)d_in[9];
  const float* wout = (const float*)d_in[10];
  const float* bout = (const float*)d_in[11];

  char* ws = (char*)d_ws;
  size_t off = 0;
  auto alloc = [&](size_t bytes) {
    void* p = ws + off;
    off = (off + bytes + 255) & ~(size_t)255;
    return p;
  };
  int*         orow = (int*)alloc((size_t)T_ * B_ * 4);
  signed char* mm   = (signed char*)alloc((size_t)T_ * B_);
  float*       cbuf = (float*)alloc((size_t)B_ * U_ * 4);
  _Float16*    h    = (_Float16*)alloc((size_t)B_ * U_ * 2);
  _Float16*    r0   = (_Float16*)alloc((size_t)B_ * U_ * 2);
  _Float16*    r1   = (_Float16*)alloc((size_t)B_ * U_ * 2);
  _Float16*    og   = (_Float16*)alloc((size_t)B_ * U_ * 2);
  _Float16*    WrT  = (_Float16*)alloc((size_t)2048 * 512 * 2);
  _Float16*    W2T  = (_Float16*)alloc((size_t)512 * 1024 * 2);
  float*       Kp   = (float*)alloc(3 * 2048 * 4);
  float*       bp   = (float*)alloc(2048 * 4);
  float*       wv   = (float*)alloc(516 * 4);

  hipMemsetAsync(cbuf, 0, (size_t)B_ * U_ * 4, stream);
  hipMemsetAsync(h, 0, (size_t)B_ * U_ * 2, stream);
  hipMemsetAsync(r0, 0, (size_t)B_ * U_ * 2, stream);

  prep_weights<<<4096, 256, 0, stream>>>(Wr, wrnn, urnn, kern, bias, WrT, W2T, Kp, bp);
  prep_wv<<<2, 256, 0, stream>>>(wfc, bfc, wout, bout, wv);
  prep_mask<<<T_, 1024, 0, stream>>>(lt, orow, mm);

  _Float16* rin = r0;
  _Float16* rot = r1;
  for (int t = 0; t < T_; ++t) {
    gemm_step<0><<<dim3(64, 16), 256, 0, stream>>>(h, nullptr, WrT, x, Kp, bp,
                                                   mm + (size_t)t * B_, cbuf, og,
                                                   nullptr, nullptr, t);
    gather_h<<<2048, 256, 0, stream>>>(og, cbuf, orow + (size_t)t * B_, h);
    gemm_step<1><<<dim3(64, 4), 256, 0, stream>>>(h, rin, W2T, nullptr, nullptr, nullptr,
                                                  nullptr, nullptr, nullptr, brnn, rot, t);
    _Float16* tmp = rin; rin = rot; rot = tmp;
  }
  final_fc<<<2048, 256, 0, stream>>>(rin, wv, (float*)d_out);
}

// Round 3
// 1025.119 us; speedup vs baseline: 1.5251x; 1.5251x over previous
//
#include <hip/hip_runtime.h>
#include <stdint.h>

#define B_ 8192
#define T_ 21
#define F_ 3
#define U_ 512

typedef _Float16 f16x8 __attribute__((ext_vector_type(8)));
typedef float f32x4 __attribute__((ext_vector_type(4)));

__device__ __forceinline__ float fsigmoid(float x) { return 1.0f / (1.0f + __expf(-x)); }
__device__ __forceinline__ float ftanh_(float x) {
  float t = __expf(-2.0f * fabsf(x));
  float r = (1.0f - t) / (1.0f + t);
  return x < 0.0f ? -r : r;
}

__device__ __forceinline__ void gl_lds16(const void* g, void* l) {
  __builtin_amdgcn_global_load_lds((__attribute__((address_space(1))) void*)g,
                                   (__attribute__((address_space(3))) void*)l, 16, 0, 0);
}

// ---------------------------------------------------------------------------
// prep: transpose+pack weights to f16, pack kernel/bias with gate interleave
// packed col p for (gate g, unit u): p = 64*(u/16) + 16*g + (u%16)
// orig(p) = ((p>>4)&3)*512 + ((p>>6)<<4) + (p&15)
// ---------------------------------------------------------------------------
__global__ void prep_weights(const float* __restrict__ Wr, const float* __restrict__ wrnn,
                             const float* __restrict__ urnn, const float* __restrict__ kern,
                             const float* __restrict__ bias,
                             _Float16* __restrict__ WrT, _Float16* __restrict__ W2T,
                             float* __restrict__ Kp, float* __restrict__ bp) {
  size_t i = (size_t)blockIdx.x * 256 + threadIdx.x;
  if (i < (size_t)2048 * 512) {
    int p = (int)(i >> 9), k = (int)(i & 511);
    int orig = ((p >> 4) & 3) * 512 + ((p >> 6) << 4) + (p & 15);
    WrT[i] = (_Float16)Wr[(size_t)k * 2048 + orig];
  }
  if (i < (size_t)512 * 1024) {
    int n = (int)(i >> 10), k = (int)(i & 1023);
    float v = (k < 512) ? wrnn[(size_t)k * 512 + n] : urnn[(size_t)(k - 512) * 512 + n];
    W2T[i] = (_Float16)v;
  }
  if (i < 2048) {
    int p = (int)i;
    int orig = ((p >> 4) & 3) * 512 + ((p >> 6) << 4) + (p & 15);
    Kp[p] = kern[orig];
    Kp[2048 + p] = kern[2048 + orig];
    Kp[4096 + p] = kern[4096 + orig];
    bp[p] = bias[orig];
  }
}

__global__ void prep_wv(const float* __restrict__ wfc, const float* __restrict__ bfc,
                        const float* __restrict__ wout, const float* __restrict__ bout,
                        float* __restrict__ wv) {
  int u = blockIdx.x * 256 + threadIdx.x;
  if (u < 512) {
    float s = 0.0f;
    for (int k = 0; k < 32; ++k) s += wfc[u * 32 + k] * wout[k];
    wv[u] = s;
  }
  if (u == 0) {
    float s = 0.0f;
    for (int k = 0; k < 32; ++k) s += bfc[k] * wout[k];
    wv[512] = s + bout[0];
  }
}

// ---------------------------------------------------------------------------
// mask + o_idx + learned-row compaction.
// one block (1024 thr) per timestep; each thread owns 8 consecutive rows.
// scan1: cummax of learned index (orow forward fill); scan2: prefix-sum
// of learned counts -> compact idxL (padded to 128 with -1), Mpad[t].
// ---------------------------------------------------------------------------
__global__ void prep_mask(const int* __restrict__ lt, int* __restrict__ orow,
                          int* __restrict__ idxL, int* __restrict__ Mpad) {
  const int t = blockIdx.x;
  const int tid = threadIdx.x;
  __shared__ int sh[1024];
  __shared__ int s_any, s_first;
  if (tid == 0) { s_any = 0; s_first = 0x7fffffff; }
  __syncthreads();
  const int base = tid * 8;
  const int* row = lt + (size_t)t * B_ + base;
  int bits = 0;
#pragma unroll
  for (int j = 0; j < 8; ++j) bits |= (row[j] == 1) << j;
  if (bits) atomicOr(&s_any, 1);
  __syncthreads();
  if (tid == 0 && !s_any) bits |= 1;  // force row 0 learned
  if (bits) atomicMin(&s_first, base + __ffs(bits) - 1);
  int lmax = -1;
#pragma unroll
  for (int j = 0; j < 8; ++j)
    if ((bits >> j) & 1) lmax = base + j;
  sh[tid] = lmax;
  __syncthreads();
  for (int off = 1; off < 1024; off <<= 1) {
    int v = (tid >= off) ? sh[tid - off] : -1;
    __syncthreads();
    if (v > sh[tid]) sh[tid] = v;
    __syncthreads();
  }
  const int prefix = (tid > 0) ? sh[tid - 1] : -1;
  __syncthreads();
  const int cnt = __popc(bits);
  sh[tid] = cnt;
  __syncthreads();
  for (int off = 1; off < 1024; off <<= 1) {
    int v = (tid >= off) ? sh[tid - off] : 0;
    __syncthreads();
    sh[tid] += v;
    __syncthreads();
  }
  const int excl = sh[tid] - cnt;
  const int total = sh[1023];
  const int first = s_first;
  int run = prefix, pos = excl;
  int* orp = orow + (size_t)t * B_ + base;
  int* ixp = idxL + (size_t)t * B_;
#pragma unroll
  for (int j = 0; j < 8; ++j) {
    if ((bits >> j) & 1) { ixp[pos++] = base + j; run = base + j; }
    orp[j] = (run < 0) ? first : run;
  }
  const int padded = (total + 127) & ~127;
  if (tid < padded - total) ixp[total + tid] = -1;
  if (tid == 0) Mpad[t] = padded;
}

// ---------------------------------------------------------------------------
// GEMM body: 128x128 tile, BK=32, 4 waves (2x2), 16x16x32 f16 MFMA,
// double-buffered LDS 2-phase pipeline (STAGE next || compute current).
// MODE 0: LSTM on gathered learned rows; epilogue: +x@K+bias, gates,
//         c update + sigmoid(zo) scatter.
// MODE 1: RNN z = [h|r] @ W2T^T; epilogue tanh(+b_rnn) -> rout.
// ---------------------------------------------------------------------------
template <int MODE>
__device__ __forceinline__ void gemm_body(
    _Float16 (*__restrict__ Ab)[4096], _Float16 (*__restrict__ Bb)[4096],
    const _Float16* __restrict__ A0, const _Float16* __restrict__ A1,
    const _Float16* __restrict__ Wt, const float* __restrict__ x,
    const float* __restrict__ Kp, const float* __restrict__ bp,
    float* __restrict__ cbuf, _Float16* __restrict__ og,
    const float* __restrict__ brnn, _Float16* __restrict__ rout,
    const int* __restrict__ idxL, int mBase, int nBase, int t) {
  constexpr int K = (MODE == 0) ? 512 : 1024;
  constexpr int NT = K / 32;
  const int tid = threadIdx.x;
  const int w = tid >> 6, l = tid & 63;
  const int wm = w >> 1, wn = w & 1;
  const int lr = l >> 2;       // row within 16-row chunk
  const int lk = (l & 3) * 8;  // k element offset
  const int ch0 = w * 2, ch1 = w * 2 + 1;

  int ra0, ra1;  // A-source rows (gathered for MODE 0)
  if constexpr (MODE == 0) {
    int i0 = idxL[mBase + ch0 * 16 + lr];
    int i1 = idxL[mBase + ch1 * 16 + lr];
    ra0 = i0 < 0 ? 0 : i0;
    ra1 = i1 < 0 ? 0 : i1;
  } else {
    ra0 = mBase + ch0 * 16 + lr;
    ra1 = mBase + ch1 * 16 + lr;
  }

  auto STAGE = [&](int bb, int kt) {
    const int k0 = kt * 32;
    const _Float16* As = A0;
    int koff = k0;
    if constexpr (MODE == 1) {
      if (k0 >= 512) { As = A1; koff = k0 - 512; }
    }
    gl_lds16(As + (size_t)ra0 * 512 + koff + lk, (char*)Ab[bb] + ch0 * 1024);
    gl_lds16(As + (size_t)ra1 * 512 + koff + lk, (char*)Ab[bb] + ch1 * 1024);
    gl_lds16(Wt + (size_t)(nBase + ch0 * 16 + lr) * K + k0 + lk, (char*)Bb[bb] + ch0 * 1024);
    gl_lds16(Wt + (size_t)(nBase + ch1 * 16 + lr) * K + k0 + lk, (char*)Bb[bb] + ch1 * 1024);
  };

  f32x4 acc[4][4] = {};
  STAGE(0, 0);
  const int frow = l & 15;
  const int fkb = (l >> 4) * 8;
  for (int kt = 0; kt < NT; ++kt) {
    __syncthreads();  // drains previous STAGE (vmcnt(0) implicit)
    if (kt + 1 < NT) STAGE((kt + 1) & 1, kt + 1);
    const int bb = kt & 1;
    f16x8 af[4], bf[4];
#pragma unroll
    for (int m = 0; m < 4; ++m)
      af[m] = *(const f16x8*)&Ab[bb][(wm * 64 + m * 16 + frow) * 32 + fkb];
#pragma unroll
    for (int n = 0; n < 4; ++n)
      bf[n] = *(const f16x8*)&Bb[bb][(wn * 64 + n * 16 + frow) * 32 + fkb];
#pragma unroll
    for (int m = 0; m < 4; ++m)
#pragma unroll
      for (int n = 0; n < 4; ++n)
        acc[m][n] = __builtin_amdgcn_mfma_f32_16x16x32_f16(af[m], bf[n], acc[m][n], 0, 0, 0);
  }

  const int c_ = l & 15, rg = l >> 4;
  const int pB = nBase + wn * 64;
  if constexpr (MODE == 0) {
    const int u = (pB >> 6) * 16 + c_;
    float kf[4][3], bb4[4];
#pragma unroll
    for (int n = 0; n < 4; ++n) {
      int p = pB + n * 16 + c_;
      kf[n][0] = Kp[p]; kf[n][1] = Kp[2048 + p]; kf[n][2] = Kp[4096 + p];
      bb4[n] = bp[p];
    }
#pragma unroll
    for (int m = 0; m < 4; ++m) {
#pragma unroll
      for (int r = 0; r < 4; ++r) {
        int bi = idxL[mBase + wm * 64 + m * 16 + rg * 4 + r];
        if (bi < 0) continue;
        const float* xp = x + (size_t)bi * (T_ * F_) + t * F_;
        float x0 = xp[0], x1 = xp[1], x2 = xp[2];
        float zi = acc[m][0][r] + x0 * kf[0][0] + x1 * kf[0][1] + x2 * kf[0][2] + bb4[0];
        float zf = acc[m][1][r] + x0 * kf[1][0] + x1 * kf[1][1] + x2 * kf[1][2] + bb4[1];
        float zg = acc[m][2][r] + x0 * kf[2][0] + x1 * kf[2][1] + x2 * kf[2][2] + bb4[2];
        float zo = acc[m][3][r] + x0 * kf[3][0] + x1 * kf[3][1] + x2 * kf[3][2] + bb4[3];
        float ig = fsigmoid(zi), fg = fsigmoid(zf);
        float gg = ftanh_(zg), ogv = fsigmoid(zo);
        size_t ci = (size_t)bi * 512 + u;
        float cold = cbuf[ci];
        cbuf[ci] = fg * cold + ig * gg;  // all rows here are learned
        og[ci] = (_Float16)ogv;
      }
    }
  } else {
#pragma unroll
    for (int m = 0; m < 4; ++m)
#pragma unroll
      for (int n = 0; n < 4; ++n) {
        int uu = pB + n * 16 + c_;
        float bn = brnn[uu];
#pragma unroll
        for (int r = 0; r < 4; ++r) {
          int b = mBase + wm * 64 + m * 16 + rg * 4 + r;
          rout[(size_t)b * 512 + uu] = (_Float16)ftanh_(acc[m][n][r] + bn);
        }
      }
  }
}

// Fused dispatch: y<16 -> LSTM(t) on learned rows; y>=16 -> RNN computing
// r(t-1) from h(t-1), r(t-2). Both read the same h buffer; independent.
__global__ __launch_bounds__(256, 2) void fused_step(
    const _Float16* __restrict__ h, const _Float16* __restrict__ rin,
    _Float16* __restrict__ rot, const _Float16* __restrict__ WrT,
    const _Float16* __restrict__ W2T, const float* __restrict__ x,
    const float* __restrict__ Kp, const float* __restrict__ bp,
    float* __restrict__ cbuf, _Float16* __restrict__ og,
    const float* __restrict__ brnn, const int* __restrict__ idxL,
    const int* __restrict__ MpadP, int t) {
  __shared__ __align__(16) _Float16 Ab[2][4096];
  __shared__ __align__(16) _Float16 Bb[2][4096];
  if (blockIdx.y < 16) {
    if ((int)blockIdx.x * 128 >= *MpadP) return;
    gemm_body<0>(Ab, Bb, h, nullptr, WrT, x, Kp, bp, cbuf, og, nullptr, nullptr,
                 idxL, blockIdx.x * 128, blockIdx.y * 128, t);
  } else {
    gemm_body<1>(Ab, Bb, h, rin, W2T, nullptr, nullptr, nullptr, nullptr, nullptr,
                 brnn, rot, nullptr, blockIdx.x * 128, ((int)blockIdx.y - 16) * 128, t);
  }
}

__global__ __launch_bounds__(256, 2) void rnn_tail(
    const _Float16* __restrict__ h, const _Float16* __restrict__ rin,
    const _Float16* __restrict__ W2T, const float* __restrict__ brnn,
    _Float16* __restrict__ rot) {
  __shared__ __align__(16) _Float16 Ab[2][4096];
  __shared__ __align__(16) _Float16 Bb[2][4096];
  gemm_body<1>(Ab, Bb, h, rin, W2T, nullptr, nullptr, nullptr, nullptr, nullptr,
               brnn, rot, nullptr, blockIdx.x * 128, blockIdx.y * 128, 0);
}

// h[b][u] = sigmoid_o[o_row[b]][u] * tanh(c[b][u])
__global__ void gather_h(const _Float16* __restrict__ og, const float* __restrict__ cbuf,
                         const int* __restrict__ orow, _Float16* __restrict__ h) {
  int g = blockIdx.x * 256 + threadIdx.x;
  int b = g >> 6, u0 = (g & 63) << 3;
  int src = orow[b];
  f16x8 ov = *(const f16x8*)(og + (size_t)src * 512 + u0);
  const float4* cp = (const float4*)(cbuf + (size_t)b * 512 + u0);
  float4 c0 = cp[0], c1 = cp[1];
  float cc[8] = {c0.x, c0.y, c0.z, c0.w, c1.x, c1.y, c1.z, c1.w};
  f16x8 hv;
#pragma unroll
  for (int j = 0; j < 8; ++j) hv[j] = (_Float16)((float)ov[j] * ftanh_(cc[j]));
  *(f16x8*)(h + (size_t)b * 512 + u0) = hv;
}

// out[b] = dot(r[b], wv) + c0  (one wave per row), fp32 output
__global__ void final_fc(const _Float16* __restrict__ r, const float* __restrict__ wv,
                         float* __restrict__ out) {
  int gw = (blockIdx.x * 256 + threadIdx.x) >> 6;
  int l = threadIdx.x & 63;
  const _Float16* rr = r + (size_t)gw * 512;
  f16x8 rv = *(const f16x8*)(rr + l * 8);
  const float4* wp = (const float4*)(wv + l * 8);
  float4 w0 = wp[0], w1 = wp[1];
  float wf[8] = {w0.x, w0.y, w0.z, w0.w, w1.x, w1.y, w1.z, w1.w};
  float s = 0.0f;
#pragma unroll
  for (int j = 0; j < 8; ++j) s += (float)rv[j] * wf[j];
  for (int o = 32; o; o >>= 1) s += __shfl_down(s, o);
  if (l == 0) out[gw] = s + wv[512];
}

extern "C" void kernel_launch(void* const* d_in, const int* in_sizes, int n_in,
                              void* d_out, int out_size, void* d_ws, size_t ws_size,
                              hipStream_t stream) {
  const float* x    = (const float*)d_in[0];
  const int*   lt   = (const int*)d_in[1];
  const float* kern = (const float*)d_in[2];
  const float* Wr   = (const float*)d_in[3];
  const float* bias = (const float*)d_in[4];
  const float* wrnn = (const float*)d_in[5];
  const float* urnn = (const float*)d_in[6];
  const float* brnn = (const float*)d_in[7];
  const float* wfc  = (const float*)d_in[8];
  const float* bfc  = (const float*)d_in[9];
  const float* wout = (const float*)d_in[10];
  const float* bout = (const float*)d_in[11];

  char* ws = (char*)d_ws;
  size_t off = 0;
  auto alloc = [&](size_t bytes) {
    void* p = ws + off;
    off = (off + bytes + 255) & ~(size_t)255;
    return p;
  };
  int*      orow = (int*)alloc((size_t)T_ * B_ * 4);
  int*      idxL = (int*)alloc((size_t)T_ * B_ * 4);
  int*      Mpad = (int*)alloc(T_ * 4);
  float*    cbuf = (float*)alloc((size_t)B_ * U_ * 4);
  _Float16* h    = (_Float16*)alloc((size_t)B_ * U_ * 2);
  _Float16* r0   = (_Float16*)alloc((size_t)B_ * U_ * 2);
  _Float16* r1   = (_Float16*)alloc((size_t)B_ * U_ * 2);
  _Float16* og   = (_Float16*)alloc((size_t)B_ * U_ * 2);
  _Float16* WrT  = (_Float16*)alloc((size_t)2048 * 512 * 2);
  _Float16* W2T  = (_Float16*)alloc((size_t)512 * 1024 * 2);
  float*    Kp   = (float*)alloc(3 * 2048 * 4);
  float*    bp   = (float*)alloc(2048 * 4);
  float*    wv   = (float*)alloc(516 * 4);

  hipMemsetAsync(cbuf, 0, (size_t)B_ * U_ * 4, stream);
  hipMemsetAsync(h, 0, (size_t)B_ * U_ * 2, stream);
  hipMemsetAsync(r0, 0, (size_t)B_ * U_ * 2, stream);

  prep_weights<<<4096, 256, 0, stream>>>(Wr, wrnn, urnn, kern, bias, WrT, W2T, Kp, bp);
  prep_wv<<<2, 256, 0, stream>>>(wfc, bfc, wout, bout, wv);
  prep_mask<<<T_, 1024, 0, stream>>>(lt, orow, idxL, Mpad);

  _Float16* rin = r0;
  _Float16* rot = r1;
  // t=0: LSTM only (no RNN step yet)
  fused_step<<<dim3(64, 16), 256, 0, stream>>>(h, nullptr, nullptr, WrT, W2T, x, Kp, bp,
                                               cbuf, og, brnn, idxL, Mpad, 0);
  gather_h<<<2048, 256, 0, stream>>>(og, cbuf, orow, h);
  for (int t = 1; t < T_; ++t) {
    fused_step<<<dim3(64, 20), 256, 0, stream>>>(h, rin, rot, WrT, W2T, x, Kp, bp,
                                                 cbuf, og, brnn,
                                                 idxL + (size_t)t * B_, Mpad + t, t);
    _Float16* tmp = rin; rin = rot; rot = tmp;  // rin now holds r(t-1)
    gather_h<<<2048, 256, 0, stream>>>(og, cbuf, orow + (size_t)t * B_, h);
  }
  // tail: r(20) from h(20), r(19)
  rnn_tail<<<dim3(64, 4), 256, 0, stream>>>(h, rin, W2T, brnn, rot);
  final_fc<<<2048, 256, 0, stream>>>(rot, wv, (float*)d_out);
}

// Round 5
// 975.614 us; speedup vs baseline: 1.6025x; 1.0507x over previous
//
#include <hip/hip_runtime.h>
#include <stdint.h>

#define B_ 8192
#define T_ 21
#define F_ 3
#define U_ 512

typedef _Float16 f16x8 __attribute__((ext_vector_type(8)));
typedef float f32x4 __attribute__((ext_vector_type(4)));

__device__ __forceinline__ float fsigmoid(float x) { return 1.0f / (1.0f + __expf(-x)); }
__device__ __forceinline__ float ftanh_(float x) {
  float t = __expf(-2.0f * fabsf(x));
  float r = (1.0f - t) / (1.0f + t);
  return x < 0.0f ? -r : r;
}

__device__ __forceinline__ void gl_lds16(const void* g, void* l) {
  __builtin_amdgcn_global_load_lds((__attribute__((address_space(1))) void*)g,
                                   (__attribute__((address_space(3))) void*)l, 16, 0, 0);
}

// ---------------------------------------------------------------------------
// prep: transpose+pack weights to f16, pack kernel/bias with gate interleave
// packed col p for (gate g, unit u): p = 64*(u/16) + 16*g + (u%16)
// orig(p) = ((p>>4)&3)*512 + ((p>>6)<<4) + (p&15)
// ---------------------------------------------------------------------------
__global__ void prep_weights(const float* __restrict__ Wr, const float* __restrict__ wrnn,
                             const float* __restrict__ urnn, const float* __restrict__ kern,
                             const float* __restrict__ bias,
                             _Float16* __restrict__ WrT, _Float16* __restrict__ W2T,
                             float* __restrict__ Kp, float* __restrict__ bp) {
  size_t i = (size_t)blockIdx.x * 256 + threadIdx.x;
  if (i < (size_t)2048 * 512) {
    int p = (int)(i >> 9), k = (int)(i & 511);
    int orig = ((p >> 4) & 3) * 512 + ((p >> 6) << 4) + (p & 15);
    WrT[i] = (_Float16)Wr[(size_t)k * 2048 + orig];
  }
  if (i < (size_t)512 * 1024) {
    int n = (int)(i >> 10), k = (int)(i & 1023);
    float v = (k < 512) ? wrnn[(size_t)k * 512 + n] : urnn[(size_t)(k - 512) * 512 + n];
    W2T[i] = (_Float16)v;
  }
  if (i < 2048) {
    int p = (int)i;
    int orig = ((p >> 4) & 3) * 512 + ((p >> 6) << 4) + (p & 15);
    Kp[p] = kern[orig];
    Kp[2048 + p] = kern[2048 + orig];
    Kp[4096 + p] = kern[4096 + orig];
    bp[p] = bias[orig];
  }
}

__global__ void prep_wv(const float* __restrict__ wfc, const float* __restrict__ bfc,
                        const float* __restrict__ wout, const float* __restrict__ bout,
                        float* __restrict__ wv) {
  int u = blockIdx.x * 256 + threadIdx.x;
  if (u < 512) {
    float s = 0.0f;
    for (int k = 0; k < 32; ++k) s += wfc[u * 32 + k] * wout[k];
    wv[u] = s;
  }
  if (u == 0) {
    float s = 0.0f;
    for (int k = 0; k < 32; ++k) s += bfc[k] * wout[k];
    wv[512] = s + bout[0];
  }
}

// ---------------------------------------------------------------------------
// mask + o_idx + learned/unlearned row compaction.
// one block (1024 thr) per timestep; each thread owns 8 consecutive rows.
// ---------------------------------------------------------------------------
__global__ void prep_mask(const int* __restrict__ lt, int* __restrict__ orow,
                          int* __restrict__ idxL, int* __restrict__ idxU,
                          int* __restrict__ Mpad) {
  const int t = blockIdx.x;
  const int tid = threadIdx.x;
  __shared__ int sh[1024];
  __shared__ int s_any, s_first;
  if (tid == 0) { s_any = 0; s_first = 0x7fffffff; }
  __syncthreads();
  const int base = tid * 8;
  const int* row = lt + (size_t)t * B_ + base;
  int bits = 0;
#pragma unroll
  for (int j = 0; j < 8; ++j) bits |= (row[j] == 1) << j;
  if (bits) atomicOr(&s_any, 1);
  __syncthreads();
  if (tid == 0 && !s_any) bits |= 1;  // force row 0 learned
  if (bits) atomicMin(&s_first, base + __ffs(bits) - 1);
  int lmax = -1;
#pragma unroll
  for (int j = 0; j < 8; ++j)
    if ((bits >> j) & 1) lmax = base + j;
  sh[tid] = lmax;
  __syncthreads();
  for (int off = 1; off < 1024; off <<= 1) {
    int v = (tid >= off) ? sh[tid - off] : -1;
    __syncthreads();
    if (v > sh[tid]) sh[tid] = v;
    __syncthreads();
  }
  const int prefix = (tid > 0) ? sh[tid - 1] : -1;
  __syncthreads();
  const int cnt = __popc(bits);
  sh[tid] = cnt;
  __syncthreads();
  for (int off = 1; off < 1024; off <<= 1) {
    int v = (tid >= off) ? sh[tid - off] : 0;
    __syncthreads();
    sh[tid] += v;
    __syncthreads();
  }
  const int excl = sh[tid] - cnt;
  const int total = sh[1023];
  const int first = s_first;
  int run = prefix, posL = excl, posU = base - excl;
  int* orp = orow + (size_t)t * B_ + base;
  int* ixL = idxL + (size_t)t * B_;
  int* ixU = idxU + (size_t)t * B_;
#pragma unroll
  for (int j = 0; j < 8; ++j) {
    if ((bits >> j) & 1) { ixL[posL++] = base + j; run = base + j; }
    else                 { ixU[posU++] = base + j; }
    orp[j] = (run < 0) ? first : run;
  }
  const int padded = (total + 127) & ~127;
  if (tid < padded - total) ixL[total + tid] = -1;
  const int totU = B_ - total;
  for (int i = totU + tid; i < B_; i += 1024) ixU[i] = -1;
  if (tid == 0) Mpad[t] = padded;
}

// ---------------------------------------------------------------------------
// GEMM body: 128x128 tile, BK=32, 4 waves (2x2), 16x16x32 f16 MFMA.
// Depth-2 prefetch, 3 LDS buffers, counted vmcnt + raw barriers.
// MODE 0: LSTM on gathered learned rows; epilogue: +x@K+bias, gates,
//         c update, sigmoid(zo) scatter, h = o*tanh(c) (learned rows).
// MODE 1: RNN z = [h|r] @ W2T^T; epilogue tanh(+b_rnn) -> rout.
// ---------------------------------------------------------------------------
template <int MODE>
__device__ __forceinline__ void gemm_body(
    _Float16 (*__restrict__ Ab)[4096], _Float16 (*__restrict__ Bb)[4096],
    const _Float16* __restrict__ A0, const _Float16* __restrict__ A1,
    const _Float16* __restrict__ Wt, const float* __restrict__ x,
    const float* __restrict__ Kp, const float* __restrict__ bp,
    float* __restrict__ cbuf, _Float16* __restrict__ og,
    _Float16* __restrict__ hnew, const float* __restrict__ brnn,
    _Float16* __restrict__ rout, const int* __restrict__ idxL,
    int mBase, int nBase, int t) {
  constexpr int K = (MODE == 0) ? 512 : 1024;
  constexpr int NT = K / 32;
  const int tid = threadIdx.x;
  const int w = tid >> 6, l = tid & 63;
  const int wm = w >> 1, wn = w & 1;
  const int lr = l >> 2;       // row within 16-row chunk
  const int lk = (l & 3) * 8;  // k element offset
  const int ch0 = w * 2, ch1 = w * 2 + 1;

  int ra0, ra1;  // A-source rows (gathered for MODE 0)
  if constexpr (MODE == 0) {
    int i0 = idxL[mBase + ch0 * 16 + lr];
    int i1 = idxL[mBase + ch1 * 16 + lr];
    ra0 = i0 < 0 ? 0 : i0;
    ra1 = i1 < 0 ? 0 : i1;
  } else {
    ra0 = mBase + ch0 * 16 + lr;
    ra1 = mBase + ch1 * 16 + lr;
  }

  auto STAGE = [&](int bb, int kt) {
    const int k0 = kt * 32;
    const _Float16* As = A0;
    int koff = k0;
    if constexpr (MODE == 1) {
      if (k0 >= 512) { As = A1; koff = k0 - 512; }
    }
    gl_lds16(As + (size_t)ra0 * 512 + koff + lk, (char*)Ab[bb] + ch0 * 1024);
    gl_lds16(As + (size_t)ra1 * 512 + koff + lk, (char*)Ab[bb] + ch1 * 1024);
    gl_lds16(Wt + (size_t)(nBase + ch0 * 16 + lr) * K + k0 + lk, (char*)Bb[bb] + ch0 * 1024);
    gl_lds16(Wt + (size_t)(nBase + ch1 * 16 + lr) * K + k0 + lk, (char*)Bb[bb] + ch1 * 1024);
  };

  f32x4 acc[4][4] = {};
  STAGE(0, 0);
  STAGE(1, 1);
  const int frow = l & 15;
  const int fkb = (l >> 4) * 8;
#pragma unroll
  for (int kt = 0; kt < NT; ++kt) {
    if (kt + 2 < NT) {
      STAGE((kt + 2) % 3, kt + 2);
      asm volatile("s_waitcnt vmcnt(8)" ::: "memory");
    } else if (kt + 1 < NT) {
      asm volatile("s_waitcnt vmcnt(4)" ::: "memory");
    } else {
      asm volatile("s_waitcnt vmcnt(0)" ::: "memory");
    }
    __builtin_amdgcn_s_barrier();
    __builtin_amdgcn_sched_barrier(0);
    const int bb = kt % 3;
    f16x8 af[4], bf[4];
#pragma unroll
    for (int m = 0; m < 4; ++m)
      af[m] = *(const f16x8*)&Ab[bb][(wm * 64 + m * 16 + frow) * 32 + fkb];
#pragma unroll
    for (int n = 0; n < 4; ++n)
      bf[n] = *(const f16x8*)&Bb[bb][(wn * 64 + n * 16 + frow) * 32 + fkb];
#pragma unroll
    for (int m = 0; m < 4; ++m)
#pragma unroll
      for (int n = 0; n < 4; ++n)
        acc[m][n] = __builtin_amdgcn_mfma_f32_16x16x32_f16(af[m], bf[n], acc[m][n], 0, 0, 0);
    __builtin_amdgcn_sched_barrier(0);
    __builtin_amdgcn_s_barrier();
  }

  const int c_ = l & 15, rg = l >> 4;
  const int pB = nBase + wn * 64;
  if constexpr (MODE == 0) {
    const int u = (pB >> 6) * 16 + c_;
    float kf[4][3], bb4[4];
#pragma unroll
    for (int n = 0; n < 4; ++n) {
      int p = pB + n * 16 + c_;
      kf[n][0] = Kp[p]; kf[n][1] = Kp[2048 + p]; kf[n][2] = Kp[4096 + p];
      bb4[n] = bp[p];
    }
#pragma unroll
    for (int m = 0; m < 4; ++m) {
#pragma unroll
      for (int r = 0; r < 4; ++r) {
        int bi = idxL[mBase + wm * 64 + m * 16 + rg * 4 + r];
        if (bi < 0) continue;
        const float* xp = x + (size_t)bi * (T_ * F_) + t * F_;
        float x0 = xp[0], x1 = xp[1], x2 = xp[2];
        float zi = acc[m][0][r] + x0 * kf[0][0] + x1 * kf[0][1] + x2 * kf[0][2] + bb4[0];
        float zf = acc[m][1][r] + x0 * kf[1][0] + x1 * kf[1][1] + x2 * kf[1][2] + bb4[1];
        float zg = acc[m][2][r] + x0 * kf[2][0] + x1 * kf[2][1] + x2 * kf[2][2] + bb4[2];
        float zo = acc[m][3][r] + x0 * kf[3][0] + x1 * kf[3][1] + x2 * kf[3][2] + bb4[3];
        float ig = fsigmoid(zi), fg = fsigmoid(zf);
        float gg = ftanh_(zg), ogv = fsigmoid(zo);
        size_t ci = (size_t)bi * 512 + u;
        float cold = cbuf[ci];
        float cnew = fg * cold + ig * gg;  // all rows here are learned
        cbuf[ci] = cnew;
        og[ci] = (_Float16)ogv;
        hnew[ci] = (_Float16)(ogv * ftanh_(cnew));
      }
    }
  } else {
#pragma unroll
    for (int m = 0; m < 4; ++m)
#pragma unroll
      for (int n = 0; n < 4; ++n) {
        int uu = pB + n * 16 + c_;
        float bn = brnn[uu];
#pragma unroll
        for (int r = 0; r < 4; ++r) {
          int b = mBase + wm * 64 + m * 16 + rg * 4 + r;
          rout[(size_t)b * 512 + uu] = (_Float16)ftanh_(acc[m][n][r] + bn);
        }
      }
  }
}

// Fused dispatch: y<16 -> LSTM(t) on learned rows (reads hprev, writes hnew);
// y>=16 -> RNN computing r(t-1) from hprev=h(t-1), rin=r(t-2). Independent.
__global__ __launch_bounds__(256, 3) void fused_step(
    const _Float16* __restrict__ hprev, _Float16* __restrict__ hnew,
    const _Float16* __restrict__ rin, _Float16* __restrict__ rot,
    const _Float16* __restrict__ WrT, const _Float16* __restrict__ W2T,
    const float* __restrict__ x, const float* __restrict__ Kp,
    const float* __restrict__ bp, float* __restrict__ cbuf,
    _Float16* __restrict__ og, const float* __restrict__ brnn,
    const int* __restrict__ idxL, const int* __restrict__ MpadP, int t) {
  __shared__ __align__(16) _Float16 Ab[3][4096];
  __shared__ __align__(16) _Float16 Bb[3][4096];
  if (blockIdx.y < 16) {
    if ((int)blockIdx.x * 128 >= *MpadP) return;
    gemm_body<0>(Ab, Bb, hprev, nullptr, WrT, x, Kp, bp, cbuf, og, hnew, nullptr,
                 nullptr, idxL, blockIdx.x * 128, blockIdx.y * 128, t);
  } else {
    gemm_body<1>(Ab, Bb, hprev, rin, W2T, nullptr, nullptr, nullptr, nullptr, nullptr,
                 nullptr, brnn, rot, nullptr, blockIdx.x * 128, ((int)blockIdx.y - 16) * 128, t);
  }
}

__global__ __launch_bounds__(256, 3) void rnn_tail(
    const _Float16* __restrict__ h, const _Float16* __restrict__ rin,
    const _Float16* __restrict__ W2T, const float* __restrict__ brnn,
    _Float16* __restrict__ rot) {
  __shared__ __align__(16) _Float16 Ab[3][4096];
  __shared__ __align__(16) _Float16 Bb[3][4096];
  gemm_body<1>(Ab, Bb, h, rin, W2T, nullptr, nullptr, nullptr, nullptr, nullptr,
               nullptr, brnn, rot, nullptr, blockIdx.x * 128, blockIdx.y * 128, 0);
}

// unlearned rows only: h[b][u] = og[orow[b]][u] * tanh(c[b][u])
__global__ void gather_h(const _Float16* __restrict__ og, const float* __restrict__ cbuf,
                         const int* __restrict__ orow, const int* __restrict__ idxU,
                         _Float16* __restrict__ h) {
  int g = blockIdx.x * 256 + threadIdx.x;
  int b = idxU[g >> 6];
  if (b < 0) return;
  int u0 = (g & 63) << 3;
  int src = orow[b];
  f16x8 ov = *(const f16x8*)(og + (size_t)src * 512 + u0);
  const float4* cp = (const float4*)(cbuf + (size_t)b * 512 + u0);
  float4 c0 = cp[0], c1 = cp[1];
  float cc[8] = {c0.x, c0.y, c0.z, c0.w, c1.x, c1.y, c1.z, c1.w};
  f16x8 hv;
#pragma unroll
  for (int j = 0; j < 8; ++j) hv[j] = (_Float16)((float)ov[j] * ftanh_(cc[j]));
  *(f16x8*)(h + (size_t)b * 512 + u0) = hv;
}

// out[b] = dot(r[b], wv) + c0  (one wave per row), fp32 output
__global__ void final_fc(const _Float16* __restrict__ r, const float* __restrict__ wv,
                         float* __restrict__ out) {
  int gw = (blockIdx.x * 256 + threadIdx.x) >> 6;
  int l = threadIdx.x & 63;
  const _Float16* rr = r + (size_t)gw * 512;
  f16x8 rv = *(const f16x8*)(rr + l * 8);
  const float4* wp = (const float4*)(wv + l * 8);
  float4 w0 = wp[0], w1 = wp[1];
  float wf[8] = {w0.x, w0.y, w0.z, w0.w, w1.x, w1.y, w1.z, w1.w};
  float s = 0.0f;
#pragma unroll
  for (int j = 0; j < 8; ++j) s += (float)rv[j] * wf[j];
  for (int o = 32; o; o >>= 1) s += __shfl_down(s, o);
  if (l == 0) out[gw] = s + wv[512];
}

extern "C" void kernel_launch(void* const* d_in, const int* in_sizes, int n_in,
                              void* d_out, int out_size, void* d_ws, size_t ws_size,
                              hipStream_t stream) {
  const float* x    = (const float*)d_in[0];
  const int*   lt   = (const int*)d_in[1];
  const float* kern = (const float*)d_in[2];
  const float* Wr   = (const float*)d_in[3];
  const float* bias = (const float*)d_in[4];
  const float* wrnn = (const float*)d_in[5];
  const float* urnn = (const float*)d_in[6];
  const float* brnn = (const float*)d_in[7];
  const float* wfc  = (const float*)d_in[8];
  const float* bfc  = (const float*)d_in[9];
  const float* wout = (const float*)d_in[10];
  const float* bout = (const float*)d_in[11];

  char* ws = (char*)d_ws;
  size_t off = 0;
  auto alloc = [&](size_t bytes) {
    void* p = ws + off;
    off = (off + bytes + 255) & ~(size_t)255;
    return p;
  };
  int*      orow = (int*)alloc((size_t)T_ * B_ * 4);
  int*      idxL = (int*)alloc((size_t)T_ * B_ * 4);
  int*      idxU = (int*)alloc((size_t)T_ * B_ * 4);
  int*      Mpad = (int*)alloc(T_ * 4);
  float*    cbuf = (float*)alloc((size_t)B_ * U_ * 4);
  _Float16* h0   = (_Float16*)alloc((size_t)B_ * U_ * 2);
  _Float16* h1   = (_Float16*)alloc((size_t)B_ * U_ * 2);
  _Float16* r0   = (_Float16*)alloc((size_t)B_ * U_ * 2);
  _Float16* r1   = (_Float16*)alloc((size_t)B_ * U_ * 2);
  _Float16* og   = (_Float16*)alloc((size_t)B_ * U_ * 2);
  _Float16* WrT  = (_Float16*)alloc((size_t)2048 * 512 * 2);
  _Float16* W2T  = (_Float16*)alloc((size_t)512 * 1024 * 2);
  float*    Kp   = (float*)alloc(3 * 2048 * 4);
  float*    bp   = (float*)alloc(2048 * 4);
  float*    wv   = (float*)alloc(516 * 4);

  hipMemsetAsync(cbuf, 0, (size_t)B_ * U_ * 4, stream);
  hipMemsetAsync(h0, 0, (size_t)B_ * U_ * 2, stream);
  hipMemsetAsync(r0, 0, (size_t)B_ * U_ * 2, stream);

  prep_weights<<<4096, 256, 0, stream>>>(Wr, wrnn, urnn, kern, bias, WrT, W2T, Kp, bp);
  prep_wv<<<2, 256, 0, stream>>>(wfc, bfc, wout, bout, wv);
  prep_mask<<<T_, 1024, 0, stream>>>(lt, orow, idxL, idxU, Mpad);

  _Float16* hbuf[2] = {h0, h1};
  _Float16* rin = r0;
  _Float16* rot = r1;
  // step t reads hbuf[t&1] (= h(t-1)), writes hbuf[(t+1)&1] (= h(t))
  fused_step<<<dim3(64, 16), 256, 0, stream>>>(h0, h1, nullptr, nullptr, WrT, W2T, x,
                                               Kp, bp, cbuf, og, brnn, idxL, Mpad, 0);
  gather_h<<<2048, 256, 0, stream>>>(og, cbuf, orow, idxU, h1);
  for (int t = 1; t < T_; ++t) {
    _Float16* hp = hbuf[t & 1];
    _Float16* hn = hbuf[(t + 1) & 1];
    fused_step<<<dim3(64, 20), 256, 0, stream>>>(hp, hn, rin, rot, WrT, W2T, x, Kp, bp,
                                                 cbuf, og, brnn,
                                                 idxL + (size_t)t * B_, Mpad + t, t);
    _Float16* tmp = rin; rin = rot; rot = tmp;  // rin now holds r(t-1)
    gather_h<<<2048, 256, 0, stream>>>(og, cbuf, orow + (size_t)t * B_,
                                       idxU + (size_t)t * B_, hn);
  }
  // tail: r(20) from h(20), which lives in hbuf[(T_-1+1)&1] = hbuf[T_&1] = hbuf[1]
  rnn_tail<<<dim3(64, 4), 256, 0, stream>>>(hbuf[T_ & 1], rin, W2T, brnn, rot);
  final_fc<<<2048, 256, 0, stream>>>(rot, wv, (float*)d_out);
}